// Round 9
// baseline (547.849 us; speedup 1.0000x reference)
//
#include <hip/hip_runtime.h>
#include <hip/hip_bf16.h>

// HighSparsityMoE v8: h-kernel rebuilt m97-style — W panels via global_load_lds
// (fire-and-forget, can't be scheduler-sunk), double-buffered LDS, per-panel
// vmcnt(0)+barrier. r8 lesson: register-rotation W prefetch left ~110K cy/block
// of latency stall (compiler sinks loads); LDS-staging breaks the reg dep chain.

#define T_TOK 2048
#define DIM   896
#define INTERN 2560
#define NEXP  16
#define TOPK  4
#define MT    64
#define IC    256
#define ICAP  133

#define SLOTGU ((size_t)80 * 56 * 512)
#define SLOTD  ((size_t)28 * 160 * 512)

typedef __attribute__((ext_vector_type(8)))  __bf16 bf16x8;
typedef __attribute__((ext_vector_type(4)))  __bf16 bf16x4;
typedef __attribute__((ext_vector_type(16))) float  f32x16;

#define GLD_LDS(GP, LP) __builtin_amdgcn_global_load_lds( \
    (const __attribute__((address_space(1))) void*)(GP), \
    (__attribute__((address_space(3))) void*)(LP), 16, 0, 0)

// barrier that does NOT drain vmcnt (keeps global prefetch in flight)
__device__ __forceinline__ void panel_barrier() {
  asm volatile("s_waitcnt lgkmcnt(0)" ::: "memory");
  __builtin_amdgcn_s_barrier();
  __builtin_amdgcn_sched_barrier(0);
}

// dense per-bucket work decode: idx -> (g, tile) using cnt[]; true if real work
__device__ __forceinline__ bool decode_work(const int* cnt, int b, int idx,
                                            int& g, int& tile) {
  int K0 = (cnt[b] + MT - 1) >> 6;
  int K1 = (cnt[b + 8] + MT - 1) >> 6;
  if (idx < K0) { g = b; tile = idx; return true; }
  idx -= K0;
  if (idx < K1) { g = b + 8; tile = idx; return true; }
  idx -= K1;
  if (idx < 4) { g = NEXP; tile = b + 8 * idx; return true; }
  return false;
}

// ---------------- K1: router ----------------
__global__ void router_k(const float* __restrict__ x, const float* __restrict__ rw,
                         int* __restrict__ cnt, float* __restrict__ Pacc,
                         float* __restrict__ facc, int* __restrict__ tok,
                         float* __restrict__ wts) {
  int lane = threadIdx.x & 63;
  int t = blockIdx.x * 4 + (threadIdx.x >> 6);
  const float* xr = x + (size_t)t * DIM;

  float acc[NEXP];
#pragma unroll
  for (int e = 0; e < NEXP; ++e) acc[e] = 0.f;
  for (int i = 0; i < DIM / 64; ++i) {
    int d = i * 64 + lane;
    float xv = xr[d];
    const float* r = rw + d * NEXP;
#pragma unroll
    for (int e = 0; e < NEXP; ++e) acc[e] = fmaf(xv, r[e], acc[e]);
  }
#pragma unroll
  for (int e = 0; e < NEXP; ++e) {
    float v = acc[e];
    v += __shfl_xor(v, 32); v += __shfl_xor(v, 16); v += __shfl_xor(v, 8);
    v += __shfl_xor(v, 4);  v += __shfl_xor(v, 2);  v += __shfl_xor(v, 1);
    acc[e] = v;
  }
  float m = acc[0];
#pragma unroll
  for (int e = 1; e < NEXP; ++e) m = fmaxf(m, acc[e]);
  float p[NEXP]; float s = 0.f;
#pragma unroll
  for (int e = 0; e < NEXP; ++e) { p[e] = __expf(acc[e] - m); s += p[e]; }
  float is = 1.f / s;
#pragma unroll
  for (int e = 0; e < NEXP; ++e) p[e] *= is;

  float pc[NEXP];
#pragma unroll
  for (int e = 0; e < NEXP; ++e) pc[e] = p[e];
  int sels[TOPK]; float svs[TOPK]; float s4 = 0.f;
#pragma unroll
  for (int k = 0; k < TOPK; ++k) {
    int best = 0; float bv = pc[0];
#pragma unroll
    for (int e = 1; e < NEXP; ++e) { if (pc[e] > bv) { bv = pc[e]; best = e; } }
    sels[k] = best; svs[k] = bv; s4 += bv;
#pragma unroll
    for (int e = 0; e < NEXP; ++e) { if (e == best) pc[e] = -1.f; }
  }
  float inv = 1.f / (s4 + 1e-8f);

  if (lane < NEXP) atomicAdd(&Pacc[lane], p[lane] * (1.f / T_TOK));
  if (lane < TOPK) {
    int e = sels[lane]; float w = svs[lane] * inv;
    atomicAdd(&facc[e], 1.f / T_TOK);
    int pos = atomicAdd(&cnt[e], 1);
    tok[e * T_TOK + pos] = t;
    wts[e * T_TOK + pos] = w;
  }
}

// ---------------- K2: balance loss + expert offsets ----------------
__global__ void loss_k(const float* __restrict__ Pacc, const float* __restrict__ facc,
                       const int* __restrict__ cnt, int* __restrict__ offs,
                       float* __restrict__ dst) {
  if (threadIdx.x == 0) {
    float s = 0.f;
    for (int e = 0; e < NEXP; ++e) s += Pacc[e] * facc[e];
    *dst = (float)NEXP * s;
    int o = 0;
    for (int e = 0; e < NEXP; ++e) { offs[e] = o; o += cnt[e]; }
    offs[NEXP] = o;
  }
}

// ---------------- K0: pack all weights into frag order (one launch) ----------
__global__ __launch_bounds__(256, 8) void packall_k(
    const float* __restrict__ Wg, const float* __restrict__ Sg,
    __hip_bfloat16* __restrict__ PG,
    const float* __restrict__ Wu, const float* __restrict__ Su,
    __hip_bfloat16* __restrict__ PU,
    const float* __restrict__ Wd, const float* __restrict__ Sd,
    __hip_bfloat16* __restrict__ PD) {
  int bid = blockIdx.x;
  int which = bid / 9520;       // 0=G, 1=U, 2=D   (9520 = 560*17)
  int r = bid % 9520;
  int z = r / 560, rr = r % 560;
  int K, N, kt, nt;
  const float *srcE, *srcS; __hip_bfloat16* dst;
  if (which < 2) {
    K = DIM; N = INTERN; kt = rr % 14; nt = rr / 14;
    srcE = which ? Wu : Wg; srcS = which ? Su : Sg; dst = which ? PU : PG;
  } else {
    K = INTERN; N = DIM; kt = rr % 40; nt = rr / 40;
    srcE = Wd; srcS = Sd; dst = PD;
  }
  const float* src = (z < NEXP) ? srcE + (size_t)z * K * N : srcS;
  __hip_bfloat16* d = dst + (size_t)z * ((size_t)(K >> 4) * (N >> 5) * 512);

  __shared__ float tile[64][65];
  int tid = threadIdx.x;
  int r0 = tid >> 4, c4 = (tid & 15) << 2;
  const float* s = src + (size_t)(kt * 64) * N + nt * 64;
#pragma unroll
  for (int it = 0; it < 4; ++it) {
    int rw_ = r0 + 16 * it;
    float4 v = *reinterpret_cast<const float4*>(s + (size_t)rw_ * N + c4);
    tile[rw_][c4] = v.x; tile[rw_][c4 + 1] = v.y;
    tile[rw_][c4 + 2] = v.z; tile[rw_][c4 + 3] = v.w;
  }
  __syncthreads();
  int lane = tid & 63, h5 = lane >> 5, c31 = lane & 31;
  int KS = K >> 4;
#pragma unroll
  for (int it = 0; it < 2; ++it) {
    int cc = (tid >> 6) + 4 * it;
    int nbl = cc >> 2, ksl = cc & 3;
    bf16x8 v;
#pragma unroll
    for (int e = 0; e < 8; ++e)
      v[e] = (__bf16)tile[ksl * 16 + 8 * h5 + e][nbl * 32 + c31];
    size_t n_blk = (size_t)nt * 2 + nbl, ks = (size_t)kt * 4 + ksl;
    *reinterpret_cast<bf16x8*>(d + ((n_blk * KS + ks) * 64 + lane) * 8) = v;
  }
}

// ---------------- K3a v8: h5_k — GEMM1+SwiGLU, W via global_load_lds ----------
__global__ __launch_bounds__(512, 4) void h5_k(
    const float* __restrict__ x, const int* __restrict__ cnt,
    const int* __restrict__ offs, const int* __restrict__ tok,
    const __hip_bfloat16* __restrict__ PG, const __hip_bfloat16* __restrict__ PU,
    __hip_bfloat16* __restrict__ H) {
  int bid = blockIdx.x;
  int ch = bid / (8 * ICAP);
  int r_ = bid % (8 * ICAP);
  int b = r_ & 7, idx = r_ >> 3;
  int g, tile;
  if (!decode_work(cnt, b, idx, g, tile)) return;
  int M = (g < NEXP) ? cnt[g] : T_TOK;
  int m0 = tile * MT;

  __shared__ int rows_s[MT];
  // W panel: [buf][wave][mat(2)][ksl(2)][1024B]  -> 32 KB per buf
  __shared__ __align__(16) char wb[2][32768];
  // X panel: [buf][64 rows][80 B] (pad-16 stride -> conflict-free b128 reads)
  __shared__ __align__(16) char xb[2][5120];
  char* hb = &wb[0][0];                           // epilogue aliases W buf 0

  int tid = threadIdx.x;
  if (tid < MT) {
    if (g < NEXP) {
      int i = m0 + tid;
      rows_s[tid] = tok[g * T_TOK + ((i < M) ? i : m0)];
    } else rows_s[tid] = m0 + tid;
  }
  __syncthreads();

  int wv = tid >> 6, lane = tid & 63;
  int h5 = lane >> 5, c31 = lane & 31;
  int srow = tid >> 3, sc8 = tid & 7;
  const float* xr = x + (size_t)rows_s[srow] * DIM;

  int slot = (g < NEXP) ? g : NEXP;
  // per-lane global frag addresses (chunk base + lane*16B)
  const __hip_bfloat16* bg = PG + (size_t)slot * SLOTGU +
      ((size_t)(ch * 8 + wv) * 56) * 512 + lane * 8;
  const __hip_bfloat16* bu = PU + (size_t)slot * SLOTGU +
      ((size_t)(ch * 8 + wv) * 56) * 512 + lane * 8;

  // issue W chunks for panel P into wb[PB]: 4 x global_load_lds dwordx4
#define ISSUE_W(PB, P) { \
    char* wdst = &wb[PB][wv * 4096]; \
    const __hip_bfloat16* gg_ = bg + (size_t)(2 * (P)) * 512; \
    const __hip_bfloat16* gu_ = bu + (size_t)(2 * (P)) * 512; \
    GLD_LDS(gg_,       wdst); \
    GLD_LDS(gg_ + 512, wdst + 1024); \
    GLD_LDS(gu_,       wdst + 2048); \
    GLD_LDS(gu_ + 512, wdst + 3072); }

#define KSTEP(PB, KSL) { \
    bf16x8 wg = *reinterpret_cast<const bf16x8*>(&wb[PB][wv * 4096 + (KSL) * 1024 + lane * 16]); \
    bf16x8 wu = *reinterpret_cast<const bf16x8*>(&wb[PB][wv * 4096 + 2048 + (KSL) * 1024 + lane * 16]); \
    bf16x8 xa = *reinterpret_cast<const bf16x8*>(&xb[PB][c31 * 80 + (KSL) * 32 + h5 * 16]); \
    bf16x8 xc = *reinterpret_cast<const bf16x8*>(&xb[PB][(c31 + 32) * 80 + (KSL) * 32 + h5 * 16]); \
    ag0 = __builtin_amdgcn_mfma_f32_32x32x16_bf16(wg, xa, ag0, 0, 0, 0); \
    ag1 = __builtin_amdgcn_mfma_f32_32x32x16_bf16(wg, xc, ag1, 0, 0, 0); \
    au0 = __builtin_amdgcn_mfma_f32_32x32x16_bf16(wu, xa, au0, 0, 0, 0); \
    au1 = __builtin_amdgcn_mfma_f32_32x32x16_bf16(wu, xc, au1, 0, 0, 0); }

#define STX_X(PB, V) { bf16x4 b4_; \
    b4_[0] = (__bf16)(V).x; b4_[1] = (__bf16)(V).y; \
    b4_[2] = (__bf16)(V).z; b4_[3] = (__bf16)(V).w; \
    *reinterpret_cast<bf16x4*>(&xb[PB][srow * 80 + sc8 * 8]) = b4_; }

  f32x16 ag0, ag1, au0, au1;
#pragma unroll
  for (int r = 0; r < 16; ++r) { ag0[r] = 0.f; ag1[r] = 0.f; au0[r] = 0.f; au1[r] = 0.f; }

  // prologue: panel 0
  float4 xv;
  ISSUE_W(0, 0)
  xv = *reinterpret_cast<const float4*>(xr + sc8 * 4);
  asm volatile("s_waitcnt vmcnt(0)" ::: "memory");
  STX_X(0, xv)
  panel_barrier();

  for (int p = 0; p < 28; ++p) {
    int pb = p & 1;
    if (p < 27) {
      ISSUE_W(pb ^ 1, p + 1)
      xv = *reinterpret_cast<const float4*>(xr + (p + 1) * 32 + sc8 * 4);
    }
    KSTEP(pb, 0) KSTEP(pb, 1)
    asm volatile("s_waitcnt vmcnt(0)" ::: "memory");
    if (p < 27) STX_X(pb ^ 1, xv)
    panel_barrier();
  }
#undef ISSUE_W
#undef KSTEP
#undef STX_X

  // SwiGLU in-register -> hb ([tok][256] bf16, swizzled); hb aliases wb[0]
#pragma unroll
  for (int mh = 0; mh < 2; ++mh) {
    int tokr = c31 + 32 * mh;
#pragma unroll
    for (int q = 0; q < 4; ++q) {
      bf16x4 hq;
#pragma unroll
      for (int j = 0; j < 4; ++j) {
        float gg = mh ? ag1[4 * q + j] : ag0[4 * q + j];
        float uu = mh ? au1[4 * q + j] : au0[4 * q + j];
        hq[j] = (__bf16)(gg / (1.f + __expf(-gg)) * uu);
      }
      int i0 = wv * 32 + 8 * q + 4 * h5;
      int byte = (tokr * 512 + i0 * 2) ^ ((tokr & 7) << 4);
      *reinterpret_cast<bf16x4*>(&hb[byte]) = hq;
    }
  }
  panel_barrier();

  // wide store hb -> H[slot][ch*256 ..+256), valid rows only (tail-tile fix)
  if (g == NEXP || m0 + srow < M) {
    int slotr = offs[g] + m0 + srow;
    int sswz = (srow & 7) << 4;
    __hip_bfloat16* hrow = H + (size_t)slotr * INTERN + ch * IC + sc8 * 32;
#pragma unroll
    for (int qq = 0; qq < 4; ++qq) {
      int byte = (srow * 512 + sc8 * 64 + qq * 16) ^ sswz;
      *reinterpret_cast<bf16x8*>(hrow + qq * 8) =
          *reinterpret_cast<const bf16x8*>(&hb[byte]);
    }
  }
}

// ---------------- K3b: g24_k — O = H @ Wd (packed Wd) — unchanged ----------
__global__ __launch_bounds__(512, 4) void g24_k(
    const int* __restrict__ cnt, const int* __restrict__ offs,
    const int* __restrict__ tok, const float* __restrict__ wts,
    const __hip_bfloat16* __restrict__ H,
    const __hip_bfloat16* __restrict__ PD, float* __restrict__ out) {
  int bid = blockIdx.x;
  int ns = bid / (8 * ICAP);
  int r_ = bid % (8 * ICAP);
  int b = r_ & 7, idx = r_ >> 3;
  int g, tile;
  if (!decode_work(cnt, b, idx, g, tile)) return;
  int M = (g < NEXP) ? cnt[g] : T_TOK;
  int m0 = tile * MT;

  __shared__ int rows_s[MT];
  __shared__ float w_s[MT];
  __shared__ __align__(16) char hp[2][16384];

  int tid = threadIdx.x;
  if (tid < MT) {
    if (g < NEXP) {
      int i = m0 + tid; bool v = i < M;
      rows_s[tid] = tok[g * T_TOK + (v ? i : m0)];
      w_s[tid]   = v ? wts[g * T_TOK + i] : 0.f;
    } else { rows_s[tid] = m0 + tid; w_s[tid] = 1.f; }
  }
  __syncthreads();

  int wv = tid >> 6, lane = tid & 63, h5 = lane >> 5, c31 = lane & 31;
  int mh = wv & 1, ng = wv >> 1;
  int col = ns * 128 + ng * 32 + c31;

  int slot = (g < NEXP) ? g : NEXP;
  const __hip_bfloat16* bd = PD + (size_t)slot * SLOTD +
      ((size_t)(ns * 4 + ng) * 160) * 512 + lane * 8;

  int slot0 = offs[g] + m0;
  const __hip_bfloat16* Hb = H + (size_t)slot0 * INTERN;

  int srow = tid >> 3, sc8 = tid & 7;
  const __hip_bfloat16* hr = Hb + (size_t)srow * INTERN + sc8 * 16;
  int sswz = (srow & 7) << 4;

  // Wd frag prefetch depth 8
  bf16x8 w0 = *reinterpret_cast<const bf16x8*>(bd);
  bf16x8 w1 = *reinterpret_cast<const bf16x8*>(bd + 512);
  bf16x8 w2 = *reinterpret_cast<const bf16x8*>(bd + 1024);
  bf16x8 w3 = *reinterpret_cast<const bf16x8*>(bd + 1536);
  bf16x8 w4 = *reinterpret_cast<const bf16x8*>(bd + 2048);
  bf16x8 w5 = *reinterpret_cast<const bf16x8*>(bd + 2560);
  bf16x8 w6 = *reinterpret_cast<const bf16x8*>(bd + 3072);
  bf16x8 w7 = *reinterpret_cast<const bf16x8*>(bd + 3584);

  // stage H panel 0
  bf16x8 t0 = *reinterpret_cast<const bf16x8*>(hr);
  bf16x8 t1 = *reinterpret_cast<const bf16x8*>(hr + 8);
  {
    int b0 = srow * 256 + sc8 * 32;
    *reinterpret_cast<bf16x8*>(&hp[0][b0 ^ sswz]) = t0;
    *reinterpret_cast<bf16x8*>(&hp[0][(b0 + 16) ^ sswz]) = t1;
  }
  panel_barrier();

  f32x16 o;
#pragma unroll
  for (int r = 0; r < 16; ++r) o[r] = 0.f;

  int arow = mh * 32 + c31;
  int aswz = (arow & 7) << 4;

#define G2STEP(KSL, WB) { \
    bf16x8 hf = *reinterpret_cast<const bf16x8*>( \
        &hp[pb][(arow * 256 + (KSL) * 32 + h5 * 16) ^ aswz]); \
    o = __builtin_amdgcn_mfma_f32_32x32x16_bf16(hf, WB, o, 0, 0, 0); \
    int tn = 8 * p + (KSL) + 8; if (tn >= 160) tn -= 160; \
    WB = *reinterpret_cast<const bf16x8*>(bd + (size_t)tn * 512); }

  for (int p = 0; p < 20; ++p) {
    int pb = p & 1;
    if (p < 19) {
      t0 = *reinterpret_cast<const bf16x8*>(hr + (p + 1) * 128);
      t1 = *reinterpret_cast<const bf16x8*>(hr + (p + 1) * 128 + 8);
    }
    G2STEP(0, w0) G2STEP(1, w1) G2STEP(2, w2) G2STEP(3, w3)
    G2STEP(4, w4) G2STEP(5, w5) G2STEP(6, w6) G2STEP(7, w7)
    if (p < 19) {
      int b0 = srow * 256 + sc8 * 32;
      *reinterpret_cast<bf16x8*>(&hp[pb ^ 1][b0 ^ sswz]) = t0;
      *reinterpret_cast<bf16x8*>(&hp[pb ^ 1][(b0 + 16) ^ sswz]) = t1;
    }
    panel_barrier();
  }
#undef G2STEP

#pragma unroll
  for (int r = 0; r < 16; ++r) {
    int row = (r & 3) + 8 * (r >> 2) + 4 * h5 + 32 * mh;
    atomicAdd(&out[(size_t)rows_s[row] * DIM + col], o[r] * w_s[row]);
  }
}

extern "C" void kernel_launch(void* const* d_in, const int* in_sizes, int n_in,
                              void* d_out, int out_size, void* d_ws, size_t ws_size,
                              hipStream_t stream) {
  const float* x  = (const float*)d_in[0];
  const float* rw = (const float*)d_in[1];
  const float* Wg = (const float*)d_in[2];
  const float* Wu = (const float*)d_in[3];
  const float* Wd = (const float*)d_in[4];
  const float* Sg = (const float*)d_in[5];
  const float* Su = (const float*)d_in[6];
  const float* Sd = (const float*)d_in[7];
  float* out = (float*)d_out;

  char* ws = (char*)d_ws;
  int*   cnt  = (int*)ws;
  float* Pacc = (float*)(ws + 64);
  float* facc = (float*)(ws + 128);
  int*   offs = (int*)(ws + 192);
  int*   tok  = (int*)(ws + 320);
  float* wts  = (float*)(ws + 320 + 131072);
  const size_t H_OFF = 262656;
  __hip_bfloat16* H = (__hip_bfloat16*)(ws + H_OFF);
  const size_t H_BYTES = (size_t)(2 * T_TOK * TOPK + T_TOK) * INTERN * 2;

  const size_t PG_OFF = H_OFF + H_BYTES;
  const size_t PBYTES = (size_t)17 * SLOTGU * 2;
  const size_t PU_OFF = PG_OFF + PBYTES;
  const size_t PD_OFF = PU_OFF + PBYTES;
  __hip_bfloat16* PG = (__hip_bfloat16*)(ws + PG_OFF);
  __hip_bfloat16* PU = (__hip_bfloat16*)(ws + PU_OFF);
  __hip_bfloat16* PD = (__hip_bfloat16*)(ws + PD_OFF);

  hipMemsetAsync(d_ws, 0, 320, stream);
  hipMemsetAsync(d_out, 0, (size_t)(T_TOK * DIM + 1) * sizeof(float), stream);

  router_k<<<T_TOK / 4, 256, 0, stream>>>(x, rw, cnt, Pacc, facc, tok, wts);
  loss_k<<<1, 64, 0, stream>>>(Pacc, facc, cnt, offs, out + (size_t)T_TOK * DIM);
  packall_k<<<28560, 256, 0, stream>>>(Wg, Sg, PG, Wu, Su, PU, Wd, Sd, PD);
  h5_k<<<10 * 8 * ICAP, 512, 0, stream>>>(x, cnt, offs, tok, PG, PU, H);
  g24_k<<<7 * 8 * ICAP, 512, 0, stream>>>(cnt, offs, tok, wts, H, PD, out);
}

// Round 13
// 537.664 us; speedup vs baseline: 1.0189x; 1.0189x over previous
//
#include <hip/hip_runtime.h>
#include <hip/hip_bf16.h>

// HighSparsityMoE v7 (REVERT to r8-passing config, 539.7 us).
// r10-r12 lesson: counted-vmcnt GLD_LDS pipelines (v9.x) failed refcheck 3x
// with race-magnitude errors despite repeated static queue audits — parked.
// This is the proven config: packed frag-order weights + dense compacted
// XCD-affine grid + reg-rotation W prefetch (depth 4/8).

#define T_TOK 2048
#define DIM   896
#define INTERN 2560
#define NEXP  16
#define TOPK  4
#define MT    64
#define IC    256
#define ICAP  133

#define SLOTGU ((size_t)80 * 56 * 512)
#define SLOTD  ((size_t)28 * 160 * 512)

typedef __attribute__((ext_vector_type(8)))  __bf16 bf16x8;
typedef __attribute__((ext_vector_type(4)))  __bf16 bf16x4;
typedef __attribute__((ext_vector_type(16))) float  f32x16;

// barrier that does NOT drain vmcnt (keeps global prefetch in flight)
__device__ __forceinline__ void panel_barrier() {
  asm volatile("s_waitcnt lgkmcnt(0)" ::: "memory");
  __builtin_amdgcn_s_barrier();
  __builtin_amdgcn_sched_barrier(0);
}

// dense per-bucket work decode: idx -> (g, tile) using cnt[]; true if real work
__device__ __forceinline__ bool decode_work(const int* cnt, int b, int idx,
                                            int& g, int& tile) {
  int K0 = (cnt[b] + MT - 1) >> 6;
  int K1 = (cnt[b + 8] + MT - 1) >> 6;
  if (idx < K0) { g = b; tile = idx; return true; }
  idx -= K0;
  if (idx < K1) { g = b + 8; tile = idx; return true; }
  idx -= K1;
  if (idx < 4) { g = NEXP; tile = b + 8 * idx; return true; }
  return false;
}

// ---------------- K1: router ----------------
__global__ void router_k(const float* __restrict__ x, const float* __restrict__ rw,
                         int* __restrict__ cnt, float* __restrict__ Pacc,
                         float* __restrict__ facc, int* __restrict__ tok,
                         float* __restrict__ wts) {
  int lane = threadIdx.x & 63;
  int t = blockIdx.x * 4 + (threadIdx.x >> 6);
  const float* xr = x + (size_t)t * DIM;

  float acc[NEXP];
#pragma unroll
  for (int e = 0; e < NEXP; ++e) acc[e] = 0.f;
  for (int i = 0; i < DIM / 64; ++i) {
    int d = i * 64 + lane;
    float xv = xr[d];
    const float* r = rw + d * NEXP;
#pragma unroll
    for (int e = 0; e < NEXP; ++e) acc[e] = fmaf(xv, r[e], acc[e]);
  }
#pragma unroll
  for (int e = 0; e < NEXP; ++e) {
    float v = acc[e];
    v += __shfl_xor(v, 32); v += __shfl_xor(v, 16); v += __shfl_xor(v, 8);
    v += __shfl_xor(v, 4);  v += __shfl_xor(v, 2);  v += __shfl_xor(v, 1);
    acc[e] = v;
  }
  float m = acc[0];
#pragma unroll
  for (int e = 1; e < NEXP; ++e) m = fmaxf(m, acc[e]);
  float p[NEXP]; float s = 0.f;
#pragma unroll
  for (int e = 0; e < NEXP; ++e) { p[e] = __expf(acc[e] - m); s += p[e]; }
  float is = 1.f / s;
#pragma unroll
  for (int e = 0; e < NEXP; ++e) p[e] *= is;

  float pc[NEXP];
#pragma unroll
  for (int e = 0; e < NEXP; ++e) pc[e] = p[e];
  int sels[TOPK]; float svs[TOPK]; float s4 = 0.f;
#pragma unroll
  for (int k = 0; k < TOPK; ++k) {
    int best = 0; float bv = pc[0];
#pragma unroll
    for (int e = 1; e < NEXP; ++e) { if (pc[e] > bv) { bv = pc[e]; best = e; } }
    sels[k] = best; svs[k] = bv; s4 += bv;
#pragma unroll
    for (int e = 0; e < NEXP; ++e) { if (e == best) pc[e] = -1.f; }
  }
  float inv = 1.f / (s4 + 1e-8f);

  if (lane < NEXP) atomicAdd(&Pacc[lane], p[lane] * (1.f / T_TOK));
  if (lane < TOPK) {
    int e = sels[lane]; float w = svs[lane] * inv;
    atomicAdd(&facc[e], 1.f / T_TOK);
    int pos = atomicAdd(&cnt[e], 1);
    tok[e * T_TOK + pos] = t;
    wts[e * T_TOK + pos] = w;
  }
}

// ---------------- K2: balance loss + expert offsets ----------------
__global__ void loss_k(const float* __restrict__ Pacc, const float* __restrict__ facc,
                       const int* __restrict__ cnt, int* __restrict__ offs,
                       float* __restrict__ dst) {
  if (threadIdx.x == 0) {
    float s = 0.f;
    for (int e = 0; e < NEXP; ++e) s += Pacc[e] * facc[e];
    *dst = (float)NEXP * s;
    int o = 0;
    for (int e = 0; e < NEXP; ++e) { offs[e] = o; o += cnt[e]; }
    offs[NEXP] = o;
  }
}

// ---------------- K0: pack all weights into frag order (one launch) ----------
__global__ __launch_bounds__(256, 8) void packall_k(
    const float* __restrict__ Wg, const float* __restrict__ Sg,
    __hip_bfloat16* __restrict__ PG,
    const float* __restrict__ Wu, const float* __restrict__ Su,
    __hip_bfloat16* __restrict__ PU,
    const float* __restrict__ Wd, const float* __restrict__ Sd,
    __hip_bfloat16* __restrict__ PD) {
  int bid = blockIdx.x;
  int which = bid / 9520;       // 0=G, 1=U, 2=D   (9520 = 560*17)
  int r = bid % 9520;
  int z = r / 560, rr = r % 560;
  int K, N, kt, nt;
  const float *srcE, *srcS; __hip_bfloat16* dst;
  if (which < 2) {
    K = DIM; N = INTERN; kt = rr % 14; nt = rr / 14;
    srcE = which ? Wu : Wg; srcS = which ? Su : Sg; dst = which ? PU : PG;
  } else {
    K = INTERN; N = DIM; kt = rr % 40; nt = rr / 40;
    srcE = Wd; srcS = Sd; dst = PD;
  }
  const float* src = (z < NEXP) ? srcE + (size_t)z * K * N : srcS;
  __hip_bfloat16* d = dst + (size_t)z * ((size_t)(K >> 4) * (N >> 5) * 512);

  __shared__ float tile[64][65];
  int tid = threadIdx.x;
  int r0 = tid >> 4, c4 = (tid & 15) << 2;
  const float* s = src + (size_t)(kt * 64) * N + nt * 64;
#pragma unroll
  for (int it = 0; it < 4; ++it) {
    int rw_ = r0 + 16 * it;
    float4 v = *reinterpret_cast<const float4*>(s + (size_t)rw_ * N + c4);
    tile[rw_][c4] = v.x; tile[rw_][c4 + 1] = v.y;
    tile[rw_][c4 + 2] = v.z; tile[rw_][c4 + 3] = v.w;
  }
  __syncthreads();
  int lane = tid & 63, h5 = lane >> 5, c31 = lane & 31;
  int KS = K >> 4;
#pragma unroll
  for (int it = 0; it < 2; ++it) {
    int cc = (tid >> 6) + 4 * it;
    int nbl = cc >> 2, ksl = cc & 3;
    bf16x8 v;
#pragma unroll
    for (int e = 0; e < 8; ++e)
      v[e] = (__bf16)tile[ksl * 16 + 8 * h5 + e][nbl * 32 + c31];
    size_t n_blk = (size_t)nt * 2 + nbl, ks = (size_t)kt * 4 + ksl;
    *reinterpret_cast<bf16x8*>(d + ((n_blk * KS + ks) * 64 + lane) * 8) = v;
  }
}

// ---------------- K3a: h4_k — GEMM1 + SwiGLU -> H (packed W) ----------------
__global__ __launch_bounds__(512, 4) void h4_k(
    const float* __restrict__ x, const int* __restrict__ cnt,
    const int* __restrict__ offs, const int* __restrict__ tok,
    const __hip_bfloat16* __restrict__ PG, const __hip_bfloat16* __restrict__ PU,
    __hip_bfloat16* __restrict__ H) {
  // dense decode: grid = 10 ch * 8 buckets * ICAP
  int bid = blockIdx.x;
  int ch = bid / (8 * ICAP);
  int r_ = bid % (8 * ICAP);
  int b = r_ & 7, idx = r_ >> 3;
  int g, tile;
  if (!decode_work(cnt, b, idx, g, tile)) return;
  int M = (g < NEXP) ? cnt[g] : T_TOK;
  int m0 = tile * MT;

  __shared__ int rows_s[MT];
  __shared__ __align__(16) char xph[32768];     // 2 x-panels; reused as hb at end
  char (*xp)[16384] = reinterpret_cast<char (*)[16384]>(xph);
  char* hb = xph;

  int tid = threadIdx.x;
  if (tid < MT) {
    if (g < NEXP) {
      int i = m0 + tid;
      rows_s[tid] = tok[g * T_TOK + ((i < M) ? i : m0)];
    } else rows_s[tid] = m0 + tid;
  }
  __syncthreads();

  int wv = tid >> 6, lane = tid & 63;
  int h5 = lane >> 5, c31 = lane & 31;

  int srow = tid >> 3, sc8 = tid & 7;
  const float* xr = x + (size_t)rows_s[srow] * DIM;
  int sswz = (srow & 7) << 4;

#define LDX(p, j) (*reinterpret_cast<const float4*>(xr + (p) * 128 + (sc8 + 8 * (j)) * 4))
#define STX(pb, j, v) { bf16x4 _b; _b[0]=(__bf16)(v).x; _b[1]=(__bf16)(v).y; \
    _b[2]=(__bf16)(v).z; _b[3]=(__bf16)(v).w; \
    *reinterpret_cast<bf16x4*>(&xp[pb][(srow * 256 + sc8 * 8 + 64 * (j)) ^ sswz]) = _b; }
#define XF(pb, row, ksl) (*reinterpret_cast<const bf16x8*>( \
    &xp[pb][((row) * 256 + (ksl) * 32 + h5 * 16) ^ (((row) & 7) << 4)]))

  int slot = (g < NEXP) ? g : NEXP;
  const __hip_bfloat16* bg = PG + (size_t)slot * SLOTGU +
      ((size_t)(ch * 8 + wv) * 56) * 512 + lane * 8;
  const __hip_bfloat16* bu = PU + (size_t)slot * SLOTGU +
      ((size_t)(ch * 8 + wv) * 56) * 512 + lane * 8;

  // W prefetch depth 4 (ks 0..3)
  bf16x8 g0 = *reinterpret_cast<const bf16x8*>(bg);
  bf16x8 g1 = *reinterpret_cast<const bf16x8*>(bg + 512);
  bf16x8 g2 = *reinterpret_cast<const bf16x8*>(bg + 1024);
  bf16x8 g3 = *reinterpret_cast<const bf16x8*>(bg + 1536);
  bf16x8 u0 = *reinterpret_cast<const bf16x8*>(bu);
  bf16x8 u1 = *reinterpret_cast<const bf16x8*>(bu + 512);
  bf16x8 u2 = *reinterpret_cast<const bf16x8*>(bu + 1024);
  bf16x8 u3 = *reinterpret_cast<const bf16x8*>(bu + 1536);

  // prologue: stage x-panel 0
  {
    float4 a0 = LDX(0, 0), a1 = LDX(0, 1), a2 = LDX(0, 2), a3 = LDX(0, 3);
    STX(0, 0, a0) STX(0, 1, a1) STX(0, 2, a2) STX(0, 3, a3)
  }
  panel_barrier();

  f32x16 ag0, ag1, au0, au1;
#pragma unroll
  for (int r = 0; r < 16; ++r) { ag0[r] = 0.f; ag1[r] = 0.f; au0[r] = 0.f; au1[r] = 0.f; }

#define STEP(S, GB, UB) { \
    bf16x8 xa = XF(pb, c31, S), xb = XF(pb, c31 + 32, S); \
    ag0 = __builtin_amdgcn_mfma_f32_32x32x16_bf16(GB, xa, ag0, 0, 0, 0); \
    ag1 = __builtin_amdgcn_mfma_f32_32x32x16_bf16(GB, xb, ag1, 0, 0, 0); \
    au0 = __builtin_amdgcn_mfma_f32_32x32x16_bf16(UB, xa, au0, 0, 0, 0); \
    au1 = __builtin_amdgcn_mfma_f32_32x32x16_bf16(UB, xb, au1, 0, 0, 0); \
    int nk = 8 * p + (S) + 4; if (nk >= 56) nk = 0; \
    GB = *reinterpret_cast<const bf16x8*>(bg + (size_t)nk * 512); \
    UB = *reinterpret_cast<const bf16x8*>(bu + (size_t)nk * 512); }

  float4 s0, s1, s2, s3;
  for (int p = 0; p < 7; ++p) {
    int pb = p & 1;
    if (p < 6) { s0 = LDX(p + 1, 0); s1 = LDX(p + 1, 1); }
    STEP(0, g0, u0) STEP(1, g1, u1) STEP(2, g2, u2)
    if (p < 6) {
      STX(pb ^ 1, 0, s0) STX(pb ^ 1, 1, s1)
      s2 = LDX(p + 1, 2); s3 = LDX(p + 1, 3);
    }
    STEP(3, g3, u3) STEP(4, g0, u0) STEP(5, g1, u1)
    if (p < 6) { STX(pb ^ 1, 2, s2) STX(pb ^ 1, 3, s3) }
    STEP(6, g2, u2) STEP(7, g3, u3)
    panel_barrier();
  }
#undef STEP

  // SwiGLU in-register -> hb ([tok][256] bf16, swizzled); hb aliases xp.
#pragma unroll
  for (int mh = 0; mh < 2; ++mh) {
    int tokr = c31 + 32 * mh;
#pragma unroll
    for (int q = 0; q < 4; ++q) {
      bf16x4 hq;
#pragma unroll
      for (int j = 0; j < 4; ++j) {
        float gg = mh ? ag1[4 * q + j] : ag0[4 * q + j];
        float uu = mh ? au1[4 * q + j] : au0[4 * q + j];
        hq[j] = (__bf16)(gg / (1.f + __expf(-gg)) * uu);
      }
      int i0 = wv * 32 + 8 * q + 4 * h5;
      int byte = (tokr * 512 + i0 * 2) ^ ((tokr & 7) << 4);
      *reinterpret_cast<bf16x4*>(&hb[byte]) = hq;
    }
  }
  panel_barrier();

  // wide store hb -> H[slot][ch*256 ..+256), valid rows only (tail-tile fix)
  if (g == NEXP || m0 + srow < M) {
    int slotr = offs[g] + m0 + srow;
    __hip_bfloat16* hrow = H + (size_t)slotr * INTERN + ch * IC + sc8 * 32;
#pragma unroll
    for (int qq = 0; qq < 4; ++qq) {
      int byte = (srow * 512 + sc8 * 64 + qq * 16) ^ sswz;
      *reinterpret_cast<bf16x8*>(hrow + qq * 8) =
          *reinterpret_cast<const bf16x8*>(&hb[byte]);
    }
  }
#undef LDX
#undef STX
#undef XF
}

// ---------------- K3b: g24_k — O = H @ Wd (packed Wd) ----------------
__global__ __launch_bounds__(512, 4) void g24_k(
    const int* __restrict__ cnt, const int* __restrict__ offs,
    const int* __restrict__ tok, const float* __restrict__ wts,
    const __hip_bfloat16* __restrict__ H,
    const __hip_bfloat16* __restrict__ PD, float* __restrict__ out) {
  int bid = blockIdx.x;
  int ns = bid / (8 * ICAP);
  int r_ = bid % (8 * ICAP);
  int b = r_ & 7, idx = r_ >> 3;
  int g, tile;
  if (!decode_work(cnt, b, idx, g, tile)) return;
  int M = (g < NEXP) ? cnt[g] : T_TOK;
  int m0 = tile * MT;

  __shared__ int rows_s[MT];
  __shared__ float w_s[MT];
  __shared__ __align__(16) char hp[2][16384];

  int tid = threadIdx.x;
  if (tid < MT) {
    if (g < NEXP) {
      int i = m0 + tid; bool v = i < M;
      rows_s[tid] = tok[g * T_TOK + (v ? i : m0)];
      w_s[tid]   = v ? wts[g * T_TOK + i] : 0.f;
    } else { rows_s[tid] = m0 + tid; w_s[tid] = 1.f; }
  }
  __syncthreads();

  int wv = tid >> 6, lane = tid & 63, h5 = lane >> 5, c31 = lane & 31;
  int mh = wv & 1, ng = wv >> 1;
  int col = ns * 128 + ng * 32 + c31;

  int slot = (g < NEXP) ? g : NEXP;
  const __hip_bfloat16* bd = PD + (size_t)slot * SLOTD +
      ((size_t)(ns * 4 + ng) * 160) * 512 + lane * 8;

  int slot0 = offs[g] + m0;
  const __hip_bfloat16* Hb = H + (size_t)slot0 * INTERN;

  int srow = tid >> 3, sc8 = tid & 7;
  const __hip_bfloat16* hr = Hb + (size_t)srow * INTERN + sc8 * 16;
  int sswz = (srow & 7) << 4;

  // Wd frag prefetch depth 8
  bf16x8 w0 = *reinterpret_cast<const bf16x8*>(bd);
  bf16x8 w1 = *reinterpret_cast<const bf16x8*>(bd + 512);
  bf16x8 w2 = *reinterpret_cast<const bf16x8*>(bd + 1024);
  bf16x8 w3 = *reinterpret_cast<const bf16x8*>(bd + 1536);
  bf16x8 w4 = *reinterpret_cast<const bf16x8*>(bd + 2048);
  bf16x8 w5 = *reinterpret_cast<const bf16x8*>(bd + 2560);
  bf16x8 w6 = *reinterpret_cast<const bf16x8*>(bd + 3072);
  bf16x8 w7 = *reinterpret_cast<const bf16x8*>(bd + 3584);

  // stage H panel 0
  bf16x8 t0 = *reinterpret_cast<const bf16x8*>(hr);
  bf16x8 t1 = *reinterpret_cast<const bf16x8*>(hr + 8);
  {
    int b0 = srow * 256 + sc8 * 32;
    *reinterpret_cast<bf16x8*>(&hp[0][b0 ^ sswz]) = t0;
    *reinterpret_cast<bf16x8*>(&hp[0][(b0 + 16) ^ sswz]) = t1;
  }
  panel_barrier();

  f32x16 o;
#pragma unroll
  for (int r = 0; r < 16; ++r) o[r] = 0.f;

  int arow = mh * 32 + c31;
  int aswz = (arow & 7) << 4;

#define G2STEP(KSL, WB) { \
    bf16x8 hf = *reinterpret_cast<const bf16x8*>( \
        &hp[pb][(arow * 256 + (KSL) * 32 + h5 * 16) ^ aswz]); \
    o = __builtin_amdgcn_mfma_f32_32x32x16_bf16(hf, WB, o, 0, 0, 0); \
    int tn = 8 * p + (KSL) + 8; if (tn >= 160) tn -= 160; \
    WB = *reinterpret_cast<const bf16x8*>(bd + (size_t)tn * 512); }

  for (int p = 0; p < 20; ++p) {
    int pb = p & 1;
    if (p < 19) {
      t0 = *reinterpret_cast<const bf16x8*>(hr + (p + 1) * 128);
      t1 = *reinterpret_cast<const bf16x8*>(hr + (p + 1) * 128 + 8);
    }
    G2STEP(0, w0) G2STEP(1, w1) G2STEP(2, w2) G2STEP(3, w3)
    G2STEP(4, w4) G2STEP(5, w5) G2STEP(6, w6) G2STEP(7, w7)
    if (p < 19) {
      int b0 = srow * 256 + sc8 * 32;
      *reinterpret_cast<bf16x8*>(&hp[pb ^ 1][b0 ^ sswz]) = t0;
      *reinterpret_cast<bf16x8*>(&hp[pb ^ 1][(b0 + 16) ^ sswz]) = t1;
    }
    panel_barrier();
  }
#undef G2STEP

#pragma unroll
  for (int r = 0; r < 16; ++r) {
    int row = (r & 3) + 8 * (r >> 2) + 4 * h5 + 32 * mh;
    atomicAdd(&out[(size_t)rows_s[row] * DIM + col], o[r] * w_s[row]);
  }
}

extern "C" void kernel_launch(void* const* d_in, const int* in_sizes, int n_in,
                              void* d_out, int out_size, void* d_ws, size_t ws_size,
                              hipStream_t stream) {
  const float* x  = (const float*)d_in[0];
  const float* rw = (const float*)d_in[1];
  const float* Wg = (const float*)d_in[2];
  const float* Wu = (const float*)d_in[3];
  const float* Wd = (const float*)d_in[4];
  const float* Sg = (const float*)d_in[5];
  const float* Su = (const float*)d_in[6];
  const float* Sd = (const float*)d_in[7];
  float* out = (float*)d_out;

  char* ws = (char*)d_ws;
  int*   cnt  = (int*)ws;
  float* Pacc = (float*)(ws + 64);
  float* facc = (float*)(ws + 128);
  int*   offs = (int*)(ws + 192);
  int*   tok  = (int*)(ws + 320);
  float* wts  = (float*)(ws + 320 + 131072);
  const size_t H_OFF = 262656;
  __hip_bfloat16* H = (__hip_bfloat16*)(ws + H_OFF);
  const size_t H_BYTES = (size_t)(2 * T_TOK * TOPK + T_TOK) * INTERN * 2;

  const size_t PG_OFF = H_OFF + H_BYTES;
  const size_t PBYTES = (size_t)17 * SLOTGU * 2;
  const size_t PU_OFF = PG_OFF + PBYTES;
  const size_t PD_OFF = PU_OFF + PBYTES;
  __hip_bfloat16* PG = (__hip_bfloat16*)(ws + PG_OFF);
  __hip_bfloat16* PU = (__hip_bfloat16*)(ws + PU_OFF);
  __hip_bfloat16* PD = (__hip_bfloat16*)(ws + PD_OFF);

  hipMemsetAsync(d_ws, 0, 320, stream);
  hipMemsetAsync(d_out, 0, (size_t)(T_TOK * DIM + 1) * sizeof(float), stream);

  router_k<<<T_TOK / 4, 256, 0, stream>>>(x, rw, cnt, Pacc, facc, tok, wts);
  loss_k<<<1, 64, 0, stream>>>(Pacc, facc, cnt, offs, out + (size_t)T_TOK * DIM);
  packall_k<<<28560, 256, 0, stream>>>(Wg, Sg, PG, Wu, Su, PU, Wd, Sd, PD);
  h4_k<<<10 * 8 * ICAP, 512, 0, stream>>>(x, cnt, offs, tok, PG, PU, H);
  g24_k<<<7 * 8 * ICAP, 512, 0, stream>>>(cnt, offs, tok, wts, H, PD, out);
}